// Round 4
// baseline (1714.507 us; speedup 1.0000x reference)
//
#include <hip/hip_runtime.h>
#include <hip/hip_bf16.h>

// CharDecoder: T=21, B=4096, H=1024, E=50, V=96
// d_out: scores(T,B,V) fp32 | h_T(B,H) | c_T(B,H)

#define T_STEPS 21
#define BSZ 4096
#define HDIM 1024
#define VOCAB 96
#define EDIM 50

typedef __attribute__((ext_vector_type(8))) short short8;
typedef __attribute__((ext_vector_type(4))) float f32x4;

#define GLL16(g, l)                                                        \
  __builtin_amdgcn_global_load_lds(                                        \
      (const __attribute__((address_space(1))) void*)(g),                  \
      (__attribute__((address_space(3))) void*)(l), 16, 0, 0)

__device__ __forceinline__ float sigmoidf_fast(float x) {
  return 1.0f / (1.0f + __expf(-x));
}
__device__ __forceinline__ float tanhf_fast(float x) {
  return 2.0f / (1.0f + __expf(-2.0f * x)) - 1.0f;
}

// ---- prep: fp32 -> bf16 weight/state conversion -------------------------
__global__ void prep_convert(const float* __restrict__ Whh_f,
                             const float* __restrict__ Wout_f,
                             const float* __restrict__ h0,
                             __hip_bfloat16* __restrict__ Whh,
                             __hip_bfloat16* __restrict__ Wout,
                             __hip_bfloat16* __restrict__ hb0) {
  int idx = blockIdx.x * 256 + threadIdx.x;
  if (idx < 4 * HDIM * HDIM) {
    Whh[idx] = __float2bfloat16(Whh_f[idx]);
    hb0[idx] = __float2bfloat16(h0[idx]);
  }
  if (idx < VOCAB * HDIM) Wout[idx] = __float2bfloat16(Wout_f[idx]);
}

// ---- prep: P[v][g] = emb[v] . W_ih[g] + b_ih[g] + b_hh[g] ---------------
__global__ void prep_ptable(const float* __restrict__ emb,
                            const float* __restrict__ Wih,
                            const float* __restrict__ bih,
                            const float* __restrict__ bhh,
                            float* __restrict__ P) {
  int idx = blockIdx.x * 256 + threadIdx.x;  // 96*4096
  int v = idx >> 12, g = idx & 4095;
  const float* er = emb + v * EDIM;
  const float* wr = Wih + g * EDIM;
  float s = bih[g] + bhh[g];
#pragma unroll 10
  for (int e = 0; e < EDIM; ++e) s += er[e] * wr[e];
  P[idx] = s;
}

// ---- fused LSTM step: gates GEMM (bf16 MFMA) + elementwise --------------
// Block: 128 batch rows x 32 hidden units (128 N-cols: n' = q*64+gate*16+u).
// LDS is FRAGMENT-MAJOR: 1 KiB block per (rowgroup g, frag, k-half); lane l
// of the reading wave finds its whole 16B fragment at base + l*16. All
// ds_read_b128 are uniform_base + lane*16 -> conflict-free, addr is one
// loop-invariant VGPR + immediate offset. GLL16 source is per-lane, so the
// staging permutation is done on the *global* address side.
template <bool LAST>
__global__ __launch_bounds__(256, 3) void lstm_step_kernel(
    const int* __restrict__ ids,               // B ints (this t)
    const __hip_bfloat16* __restrict__ hprev,  // B x H
    const __hip_bfloat16* __restrict__ Whh,    // 4H x H (torch order i,f,g,o)
    const float* __restrict__ P,               // V x 4H
    const float* __restrict__ c_in,            // B x H
    float* __restrict__ c_out,                 // B x H
    __hip_bfloat16* __restrict__ hnext,        // B x H
    float* __restrict__ hf32)                  // B x H (LAST only)
{
  __shared__ __align__(16) char smem[49152];
  __hip_bfloat16* sA = (__hip_bfloat16*)smem;            // 16 frag-blocks
  __hip_bfloat16* sB = (__hip_bfloat16*)(smem + 16384);  // 16 frag-blocks
  float* sP = (float*)smem;                              // [384][32] post-loop

  const int tid = threadIdx.x;
  const int wave = tid >> 6;
  const int lane = tid & 63;
  const int m0 = blockIdx.x * 128;
  const int j0 = blockIdx.y * 32;

  f32x4 acc[4][4] = {};  // [m-frag][gate]

  const int l15 = lane & 15;
  const int lk8 = (lane >> 4) * 8;  // k-chunk within fragment (elems)

  // staging sources: issue i stages frag-block b = wave*4+i
  // block b -> (g = b>>3, fr = (b>>1)&3, kb = b&1)
  const __hip_bfloat16* srcA[4];
  const __hip_bfloat16* srcB[4];
#pragma unroll
  for (int i = 0; i < 4; ++i) {
    int b = wave * 4 + i;
    int g = b >> 3, fr = (b >> 1) & 3, kb = b & 1;
    srcA[i] = hprev + (size_t)(m0 + g * 64 + fr * 16 + l15) * HDIM + kb * 32 + lk8;
    int brow = fr * HDIM + j0 + g * 16 + l15;  // gate=fr, q=g
    srcB[i] = Whh + (size_t)brow * HDIM + kb * 32 + lk8;
  }

  const int g = wave >> 1;   // A row-group for this wave
  const int gn = wave & 1;   // B col-group
  const int u16 = lane & 15;
  const int k16q = lane >> 4;

  for (int k0 = 0; k0 < HDIM; k0 += 64) {
#pragma unroll
    for (int i = 0; i < 4; ++i) {
      GLL16(srcA[i] + k0, &sA[(wave * 4 + i) * 512]);
      GLL16(srcB[i] + k0, &sB[(wave * 4 + i) * 512]);
    }
    __syncthreads();
#pragma unroll
    for (int kb = 0; kb < 2; ++kb) {
      short8 af[4], bf[4];
#pragma unroll
      for (int mi = 0; mi < 4; ++mi)
        af[mi] = *(const short8*)&sA[((g * 4 + mi) * 2 + kb) * 512 + lane * 8];
#pragma unroll
      for (int ni = 0; ni < 4; ++ni)
        bf[ni] = *(const short8*)&sB[((gn * 4 + ni) * 2 + kb) * 512 + lane * 8];
#pragma unroll
      for (int mi = 0; mi < 4; ++mi)
#pragma unroll
        for (int ni = 0; ni < 4; ++ni)
          acc[mi][ni] = __builtin_amdgcn_mfma_f32_16x16x32_bf16(
              af[mi], bf[ni], acc[mi][ni], 0, 0, 0);
    }
    __syncthreads();
  }

  // stage P-slice into (dead) sA/sB space: sP[p][32], p = v*4+gate
  {
    const int pchunk = lane & 7;  // 16B (4-float) chunk within 32-float row
#pragma unroll
    for (int i = 0; i < 12; ++i) {
      int p = wave * 96 + i * 8 + (lane >> 3);
      int v = p >> 2, gate = p & 3;
      GLL16(P + (size_t)v * 4096 + gate * 1024 + j0 + pchunk * 4,
            &sP[(wave * 96 + i * 8) * 32]);
    }
  }
  __syncthreads();

  // epilogue: all 4 gates of unit j live in this lane across n-frags
  const int jo = gn * 16 + u16;  // j - j0
  const int j = j0 + jo;
  const int rb = m0 + g * 64 + k16q * 4;
#pragma unroll
  for (int mi = 0; mi < 4; ++mi) {
#pragma unroll
    for (int r = 0; r < 4; ++r) {
      int row = rb + mi * 16 + r;
      int id = ids[row];
      const float* Pr = &sP[id * 128 + jo];
      float iv = acc[mi][0][r] + Pr[0];
      float fv = acc[mi][1][r] + Pr[32];
      float gv = acc[mi][2][r] + Pr[64];
      float ov = acc[mi][3][r] + Pr[96];
      iv = sigmoidf_fast(iv);
      fv = sigmoidf_fast(fv);
      gv = tanhf_fast(gv);
      ov = sigmoidf_fast(ov);
      size_t off = (size_t)row * HDIM + j;
      float cc = fv * c_in[off] + iv * gv;
      c_out[off] = cc;
      float hh = ov * tanhf_fast(cc);
      hnext[off] = __float2bfloat16(hh);
      if (LAST) hf32[off] = hh;
    }
  }
}

// ---- scores: LDS-tiled GEMM, 128 rows x 96 cols per block, BK=128 -------
__global__ __launch_bounds__(256, 2) void scores_kernel(
    const __hip_bfloat16* __restrict__ h,     // rows x H (bf16)
    const __hip_bfloat16* __restrict__ Wout,  // 96 x H
    const float* __restrict__ bout,           // 96
    float* __restrict__ out)                  // rows x 96
{
  __shared__ __align__(16) __hip_bfloat16 sA[128 * 128];  // 32 KB
  __shared__ __align__(16) __hip_bfloat16 sB[96 * 128];   // 24 KB

  const int tid = threadIdx.x;
  const int wave = tid >> 6, lane = tid & 63;
  const int u16 = lane & 15, k16q = lane >> 4;
  const long r0 = (long)blockIdx.x * 128;

  f32x4 acc[2][6] = {};  // wave: 32 rows x 96 cols

  const int srow4 = lane >> 4;  // staging: row within group of 4
  const int sslot = lane & 15;  // 16B slot within 256B row-chunk

  for (int k0 = 0; k0 < HDIM; k0 += 128) {
#pragma unroll
    for (int i = 0; i < 8; ++i) {  // A: 32 rows/wave
      int row = wave * 32 + i * 4 + srow4;
      int gg = sslot ^ (row & 15);
      GLL16(h + (r0 + row) * HDIM + k0 + gg * 8, &sA[(wave * 32 + i * 4) * 128]);
    }
#pragma unroll
    for (int i = 0; i < 6; ++i) {  // B: 24 rows/wave
      int row = wave * 24 + i * 4 + srow4;
      int gg = sslot ^ (row & 15);
      GLL16(Wout + (size_t)row * HDIM + k0 + gg * 8,
            &sB[(wave * 24 + i * 4) * 128]);
    }
    __syncthreads();
#pragma unroll
    for (int kk = 0; kk < 128; kk += 32) {
      const int sl = (((kk >> 3) + k16q) ^ u16) * 8;
      short8 af[2], bf[6];
#pragma unroll
      for (int mi = 0; mi < 2; ++mi)
        af[mi] = *(const short8*)&sA[(wave * 32 + mi * 16 + u16) * 128 + sl];
#pragma unroll
      for (int ni = 0; ni < 6; ++ni)
        bf[ni] = *(const short8*)&sB[(ni * 16 + u16) * 128 + sl];
#pragma unroll
      for (int mi = 0; mi < 2; ++mi)
#pragma unroll
        for (int ni = 0; ni < 6; ++ni)
          acc[mi][ni] = __builtin_amdgcn_mfma_f32_16x16x32_bf16(
              af[mi], bf[ni], acc[mi][ni], 0, 0, 0);
    }
    __syncthreads();
  }

#pragma unroll
  for (int ni = 0; ni < 6; ++ni) {
    int v = ni * 16 + u16;
    float bv = bout[v];
#pragma unroll
    for (int mi = 0; mi < 2; ++mi)
#pragma unroll
      for (int r = 0; r < 4; ++r) {
        long grow = r0 + wave * 32 + mi * 16 + k16q * 4 + r;
        out[grow * VOCAB + v] = acc[mi][ni][r] + bv;
      }
  }
}

extern "C" void kernel_launch(void* const* d_in, const int* in_sizes, int n_in,
                              void* d_out, int out_size, void* d_ws, size_t ws_size,
                              hipStream_t stream) {
  const int* ids = (const int*)d_in[0];
  const float* h0 = (const float*)d_in[1];
  const float* c0 = (const float*)d_in[2];
  const float* emb = (const float*)d_in[3];
  const float* Wih = (const float*)d_in[4];
  const float* Whh_f = (const float*)d_in[5];
  const float* bih = (const float*)d_in[6];
  const float* bhh = (const float*)d_in[7];
  const float* Wout_f = (const float*)d_in[8];
  const float* bout = (const float*)d_in[9];

  float* out = (float*)d_out;
  float* scores = out;                                  // T*B*V
  float* hT = out + (size_t)T_STEPS * BSZ * VOCAB;      // B*H
  float* cT = hT + (size_t)BSZ * HDIM;                  // B*H

  const size_t BH = (size_t)BSZ * HDIM;
  char* w = (char*)d_ws;
  float* P = (float*)w;              w += (size_t)VOCAB * 4096 * 4;
  __hip_bfloat16* Whh = (__hip_bfloat16*)w;  w += (size_t)4 * HDIM * HDIM * 2;
  __hip_bfloat16* Wout = (__hip_bfloat16*)w; w += (size_t)VOCAB * HDIM * 2;
  __hip_bfloat16* hts = (__hip_bfloat16*)w;  // 22*BH (full) or 2*BH (pingpong)
  size_t base = (size_t)VOCAB * 4096 * 4 + (size_t)4 * HDIM * HDIM * 2 +
                (size_t)VOCAB * HDIM * 2;
  const bool full = ws_size >= base + (size_t)(T_STEPS + 1) * BH * 2;

  prep_convert<<<dim3((4 * HDIM * HDIM + 255) / 256), dim3(256), 0, stream>>>(
      Whh_f, Wout_f, h0, Whh, Wout, hts);
  prep_ptable<<<dim3((VOCAB * 4096) / 256), dim3(256), 0, stream>>>(
      emb, Wih, bih, bhh, P);

  for (int t = 0; t < T_STEPS; ++t) {
    __hip_bfloat16* hp = hts + (full ? (size_t)t * BH : (size_t)(t & 1) * BH);
    __hip_bfloat16* hn = hts + (full ? (size_t)(t + 1) * BH : (size_t)((t + 1) & 1) * BH);
    const float* cin = (t == 0) ? c0 : cT;
    if (t == T_STEPS - 1) {
      lstm_step_kernel<true><<<dim3(32, 32), dim3(256), 0, stream>>>(
          ids + (size_t)t * BSZ, hp, Whh, P, cin, cT, hn, hT);
    } else {
      lstm_step_kernel<false><<<dim3(32, 32), dim3(256), 0, stream>>>(
          ids + (size_t)t * BSZ, hp, Whh, P, cin, cT, hn, nullptr);
    }
    if (!full) {
      scores_kernel<<<dim3(BSZ / 128), dim3(256), 0, stream>>>(
          hn, Wout, bout, scores + (size_t)t * BSZ * VOCAB);
    }
  }
  if (full) {
    scores_kernel<<<dim3(T_STEPS * BSZ / 128), dim3(256), 0, stream>>>(
        hts + BH, Wout, bout, scores);
  }
}

// Round 5
// 1187.796 us; speedup vs baseline: 1.4434x; 1.4434x over previous
//
#include <hip/hip_runtime.h>
#include <hip/hip_bf16.h>

// CharDecoder: T=21, B=4096, H=1024, E=50, V=96
// d_out: scores(T,B,V) fp32 | h_T(B,H) | c_T(B,H)

#define T_STEPS 21
#define BSZ 4096
#define HDIM 1024
#define VOCAB 96
#define EDIM 50

typedef __attribute__((ext_vector_type(8))) short short8;
typedef __attribute__((ext_vector_type(4))) float f32x4;

#define GLL16(g, l)                                                        \
  __builtin_amdgcn_global_load_lds(                                        \
      (const __attribute__((address_space(1))) void*)(g),                  \
      (__attribute__((address_space(3))) void*)(l), 16, 0, 0)

__device__ __forceinline__ float sigmoidf_fast(float x) {
  return 1.0f / (1.0f + __expf(-x));
}
__device__ __forceinline__ float tanhf_fast(float x) {
  return 2.0f / (1.0f + __expf(-2.0f * x)) - 1.0f;
}

// ---- prep: fp32 -> bf16 weight/state conversion -------------------------
__global__ void prep_convert(const float* __restrict__ Whh_f,
                             const float* __restrict__ Wout_f,
                             const float* __restrict__ h0,
                             __hip_bfloat16* __restrict__ Whh,
                             __hip_bfloat16* __restrict__ Wout,
                             __hip_bfloat16* __restrict__ hb0) {
  int idx = blockIdx.x * 256 + threadIdx.x;
  if (idx < 4 * HDIM * HDIM) {
    Whh[idx] = __float2bfloat16(Whh_f[idx]);
    hb0[idx] = __float2bfloat16(h0[idx]);
  }
  if (idx < VOCAB * HDIM) Wout[idx] = __float2bfloat16(Wout_f[idx]);
}

// ---- prep: Pb[jb][v][gate][32 units] (bf16) = emb.W_ih + b_ih + b_hh ----
__global__ void prep_ptable(const float* __restrict__ emb,
                            const float* __restrict__ Wih,
                            const float* __restrict__ bih,
                            const float* __restrict__ bhh,
                            __hip_bfloat16* __restrict__ Pb) {
  int idx = blockIdx.x * 256 + threadIdx.x;  // 96*4096
  int v = idx >> 12, g = idx & 4095;         // g = gate*1024 + j
  int gate = g >> 10, j = g & 1023;
  const float* er = emb + v * EDIM;
  const float* wr = Wih + g * EDIM;
  float s = bih[g] + bhh[g];
#pragma unroll 10
  for (int e = 0; e < EDIM; ++e) s += er[e] * wr[e];
  Pb[(size_t)(j >> 5) * 12288 + v * 128 + gate * 32 + (j & 31)] =
      __float2bfloat16(s);
}

// ---- fused LSTM step: gates GEMM (bf16 MFMA) + elementwise --------------
// Block: 128 batch rows x 32 hidden units (128 N-cols: n' = q*64+gate*16+u).
// R2-proven K-loop (XOR-swizzled LDS). LDS shrunk to 32 KB: P table staged
// as bf16 into the (dead) sA/sB space after the K-loop. 1D grid with XCD
// swizzle so each XCD owns 4 j-tiles (1 MB of Whh -> L2-resident).
template <bool LAST>
__global__ __launch_bounds__(256, 3) void lstm_step_kernel(
    const int* __restrict__ ids,               // B ints (this t)
    const __hip_bfloat16* __restrict__ hprev,  // B x H
    const __hip_bfloat16* __restrict__ Whh,    // 4H x H (torch order i,f,g,o)
    const __hip_bfloat16* __restrict__ Pb,     // 32 x 96 x 128 (bf16)
    const float* __restrict__ c_in,            // B x H
    float* __restrict__ c_out,                 // B x H
    __hip_bfloat16* __restrict__ hnext,        // B x H
    float* __restrict__ hf32)                  // B x H (LAST only)
{
  __shared__ __align__(16) char smem[32768];
  __hip_bfloat16* sA = (__hip_bfloat16*)smem;            // [128][64]
  __hip_bfloat16* sB = (__hip_bfloat16*)(smem + 16384);  // [128][64]
  __hip_bfloat16* sPb = (__hip_bfloat16*)smem;           // [96][128] post-loop

  const int tid = threadIdx.x;
  const int wave = tid >> 6;
  const int lane = tid & 63;
  const int bid = blockIdx.x;
  const int jt = (bid & 7) * 4 + ((bid >> 3) & 3);  // XCD-local j-tile
  const int mt = bid >> 5;
  const int m0 = mt * 128;
  const int j0 = jt * 32;

  f32x4 acc[4][4] = {};  // [m-frag][gate]

  // staging: wave stages 32 rows (4 issues x 8 rows); XOR swizzle on source
  const int lrow = lane >> 3;                // 0..7
  const int lcol = ((lane & 7) ^ lrow) * 8;  // swizzled global chunk (elems)

  int brow_g[4];
#pragma unroll
  for (int i = 0; i < 4; ++i) {
    int n = wave * 32 + i * 8 + lrow;  // n' in [0,128)
    int q = n >> 6, gate = (n >> 4) & 3, u = n & 15;
    brow_g[i] = gate * HDIM + j0 + q * 16 + u;  // W_hh global row
  }
  const __hip_bfloat16* Abase =
      hprev + (size_t)(m0 + wave * 32 + lrow) * HDIM + lcol;

  const int mw = (wave >> 1) * 64;
  const int gn = wave & 1;
  const int u16 = lane & 15;
  const int k16q = lane >> 4;

  // epilogue coordinates (known early -> prefetch c_in)
  const int jo = gn * 16 + u16;  // j - j0
  const int j = j0 + jo;
  const int rb = m0 + mw + k16q * 4;
  float cpre[4][4];
#pragma unroll
  for (int mi = 0; mi < 4; ++mi)
#pragma unroll
    for (int r = 0; r < 4; ++r)
      cpre[mi][r] = c_in[(size_t)(rb + mi * 16 + r) * HDIM + j];

  for (int k0 = 0; k0 < HDIM; k0 += 64) {
#pragma unroll
    for (int i = 0; i < 4; ++i) {
      GLL16(Abase + i * 8 * HDIM + k0, &sA[(wave * 32 + i * 8) * 64]);
      GLL16(Whh + (size_t)brow_g[i] * HDIM + k0 + lcol,
            &sB[(wave * 32 + i * 8) * 64]);
    }
    __syncthreads();
#pragma unroll
    for (int kk = 0; kk < 64; kk += 32) {
      const int sl = (((kk >> 3) + k16q) ^ (u16 & 7)) * 8;
      short8 af[4], bf[4];
#pragma unroll
      for (int mi = 0; mi < 4; ++mi)
        af[mi] = *(const short8*)&sA[(mw + mi * 16 + u16) * 64 + sl];
#pragma unroll
      for (int ni = 0; ni < 4; ++ni)
        bf[ni] = *(const short8*)&sB[(gn * 64 + ni * 16 + u16) * 64 + sl];
#pragma unroll
      for (int mi = 0; mi < 4; ++mi)
#pragma unroll
        for (int ni = 0; ni < 4; ++ni)
          acc[mi][ni] = __builtin_amdgcn_mfma_f32_16x16x32_bf16(
              af[mi], bf[ni], acc[mi][ni], 0, 0, 0);
    }
    __syncthreads();
  }

  // stage bf16 P-slice (24 KB, fully contiguous) into dead sA/sB space
  {
    const __hip_bfloat16* Pbj = Pb + (size_t)jt * 12288;
#pragma unroll
    for (int i = 0; i < 6; ++i)
      GLL16(Pbj + (wave * 6 + i) * 512 + lane * 8, &sPb[(wave * 6 + i) * 512]);
  }
  __syncthreads();

  // epilogue: all 4 gates of unit j live in this lane across n-frags
#pragma unroll
  for (int mi = 0; mi < 4; ++mi) {
#pragma unroll
    for (int r = 0; r < 4; ++r) {
      int row = rb + mi * 16 + r;
      int id = ids[row];
      const __hip_bfloat16* Pr = &sPb[id * 128 + jo];
      float iv = acc[mi][0][r] + __bfloat162float(Pr[0]);
      float fv = acc[mi][1][r] + __bfloat162float(Pr[32]);
      float gv = acc[mi][2][r] + __bfloat162float(Pr[64]);
      float ov = acc[mi][3][r] + __bfloat162float(Pr[96]);
      iv = sigmoidf_fast(iv);
      fv = sigmoidf_fast(fv);
      gv = tanhf_fast(gv);
      ov = sigmoidf_fast(ov);
      size_t off = (size_t)row * HDIM + j;
      float cc = fv * cpre[mi][r] + iv * gv;
      c_out[off] = cc;
      float hh = ov * tanhf_fast(cc);
      hnext[off] = __float2bfloat16(hh);
      if (LAST) hf32[off] = hh;
    }
  }
}

// ---- scores: LDS-tiled GEMM, 128 rows x 96 cols per block, BK=128 -------
__global__ __launch_bounds__(256, 2) void scores_kernel(
    const __hip_bfloat16* __restrict__ h,     // rows x H (bf16)
    const __hip_bfloat16* __restrict__ Wout,  // 96 x H
    const float* __restrict__ bout,           // 96
    float* __restrict__ out)                  // rows x 96
{
  __shared__ __align__(16) __hip_bfloat16 sA[128 * 128];  // 32 KB
  __shared__ __align__(16) __hip_bfloat16 sB[96 * 128];   // 24 KB

  const int tid = threadIdx.x;
  const int wave = tid >> 6, lane = tid & 63;
  const int u16 = lane & 15, k16q = lane >> 4;
  const long r0 = (long)blockIdx.x * 128;

  f32x4 acc[2][6] = {};  // wave: 32 rows x 96 cols

  const int srow4 = lane >> 4;  // staging: row within group of 4
  const int sslot = lane & 15;  // 16B slot within 256B row-chunk

  for (int k0 = 0; k0 < HDIM; k0 += 128) {
#pragma unroll
    for (int i = 0; i < 8; ++i) {  // A: 32 rows/wave
      int row = wave * 32 + i * 4 + srow4;
      int gg = sslot ^ (row & 15);
      GLL16(h + (r0 + row) * HDIM + k0 + gg * 8, &sA[(wave * 32 + i * 4) * 128]);
    }
#pragma unroll
    for (int i = 0; i < 6; ++i) {  // B: 24 rows/wave
      int row = wave * 24 + i * 4 + srow4;
      int gg = sslot ^ (row & 15);
      GLL16(Wout + (size_t)row * HDIM + k0 + gg * 8,
            &sB[(wave * 24 + i * 4) * 128]);
    }
    __syncthreads();
#pragma unroll
    for (int kk = 0; kk < 128; kk += 32) {
      const int sl = (((kk >> 3) + k16q) ^ u16) * 8;
      short8 af[2], bf[6];
#pragma unroll
      for (int mi = 0; mi < 2; ++mi)
        af[mi] = *(const short8*)&sA[(wave * 32 + mi * 16 + u16) * 128 + sl];
#pragma unroll
      for (int ni = 0; ni < 6; ++ni)
        bf[ni] = *(const short8*)&sB[(ni * 16 + u16) * 128 + sl];
#pragma unroll
      for (int mi = 0; mi < 2; ++mi)
#pragma unroll
        for (int ni = 0; ni < 6; ++ni)
          acc[mi][ni] = __builtin_amdgcn_mfma_f32_16x16x32_bf16(
              af[mi], bf[ni], acc[mi][ni], 0, 0, 0);
    }
    __syncthreads();
  }

#pragma unroll
  for (int ni = 0; ni < 6; ++ni) {
    int v = ni * 16 + u16;
    float bv = bout[v];
#pragma unroll
    for (int mi = 0; mi < 2; ++mi)
#pragma unroll
      for (int r = 0; r < 4; ++r) {
        long grow = r0 + wave * 32 + mi * 16 + k16q * 4 + r;
        out[grow * VOCAB + v] = acc[mi][ni][r] + bv;
      }
  }
}

extern "C" void kernel_launch(void* const* d_in, const int* in_sizes, int n_in,
                              void* d_out, int out_size, void* d_ws, size_t ws_size,
                              hipStream_t stream) {
  const int* ids = (const int*)d_in[0];
  const float* h0 = (const float*)d_in[1];
  const float* c0 = (const float*)d_in[2];
  const float* emb = (const float*)d_in[3];
  const float* Wih = (const float*)d_in[4];
  const float* Whh_f = (const float*)d_in[5];
  const float* bih = (const float*)d_in[6];
  const float* bhh = (const float*)d_in[7];
  const float* Wout_f = (const float*)d_in[8];
  const float* bout = (const float*)d_in[9];

  float* out = (float*)d_out;
  float* scores = out;                              // T*B*V
  float* hT = out + (size_t)T_STEPS * BSZ * VOCAB;  // B*H
  float* cT = hT + (size_t)BSZ * HDIM;              // B*H

  const size_t BH = (size_t)BSZ * HDIM;
  char* w = (char*)d_ws;
  __hip_bfloat16* Pb = (__hip_bfloat16*)w;   w += (size_t)32 * 12288 * 2;
  __hip_bfloat16* Whh = (__hip_bfloat16*)w;  w += (size_t)4 * HDIM * HDIM * 2;
  __hip_bfloat16* Wout = (__hip_bfloat16*)w; w += (size_t)VOCAB * HDIM * 2;
  __hip_bfloat16* hts = (__hip_bfloat16*)w;  // 22*BH (full) or 2*BH (pingpong)
  size_t base = (size_t)32 * 12288 * 2 + (size_t)4 * HDIM * HDIM * 2 +
                (size_t)VOCAB * HDIM * 2;
  const bool full = ws_size >= base + (size_t)(T_STEPS + 1) * BH * 2;

  prep_convert<<<dim3((4 * HDIM * HDIM + 255) / 256), dim3(256), 0, stream>>>(
      Whh_f, Wout_f, h0, Whh, Wout, hts);
  prep_ptable<<<dim3((VOCAB * 4096) / 256), dim3(256), 0, stream>>>(
      emb, Wih, bih, bhh, Pb);

  for (int t = 0; t < T_STEPS; ++t) {
    __hip_bfloat16* hp = hts + (full ? (size_t)t * BH : (size_t)(t & 1) * BH);
    __hip_bfloat16* hn =
        hts + (full ? (size_t)(t + 1) * BH : (size_t)((t + 1) & 1) * BH);
    const float* cin = (t == 0) ? c0 : cT;
    if (t == T_STEPS - 1) {
      lstm_step_kernel<true><<<dim3(1024), dim3(256), 0, stream>>>(
          ids + (size_t)t * BSZ, hp, Whh, Pb, cin, cT, hn, hT);
    } else {
      lstm_step_kernel<false><<<dim3(1024), dim3(256), 0, stream>>>(
          ids + (size_t)t * BSZ, hp, Whh, Pb, cin, cT, hn, nullptr);
    }
    if (!full) {
      scores_kernel<<<dim3(BSZ / 128), dim3(256), 0, stream>>>(
          hn, Wout, bout, scores + (size_t)t * BSZ * VOCAB);
    }
  }
  if (full) {
    scores_kernel<<<dim3(T_STEPS * BSZ / 128), dim3(256), 0, stream>>>(
        hts + BH, Wout, bout, scores);
  }
}